// Round 5
// baseline (372.350 us; speedup 1.0000x reference)
//
#include <hip/hip_runtime.h>
#include <hip/hip_bf16.h>
#include <cstdint>

#define S_LEN 1024
#define DMODEL 1024
#define NHEADS 16
#define DHEAD 64
#define MAXLEN 16384
#define BATCH 4

typedef __attribute__((ext_vector_type(8))) short bf16x8;
typedef __attribute__((ext_vector_type(4))) float f32x4;

// RNE f32 -> bf16 bits
__device__ inline unsigned short f2b(float f) {
  unsigned int u = __float_as_uint(f);
  unsigned int r = (u + 0x7FFFu + ((u >> 16) & 1u)) >> 16;
  return (unsigned short)r;
}
__device__ inline float b2f(unsigned short u) {
  return __uint_as_float(((unsigned int)u) << 16);
}

// Swizzled LDS element index for [R][64] bf16 rows (128B): 8 slots of 16B, slot ^= row&7.
#define LDSWZ(row, slot) (((row) << 6) + (((slot) ^ ((row) & 7)) << 3))

// ---------------- W transpose+convert: WT[n][k] bf16 = W[k][n] f32
__global__ __launch_bounds__(256) void wt_convert(const float* __restrict__ W,
                                                  unsigned short* __restrict__ WT) {
  __shared__ float t[32][33];
  const int bi = blockIdx.y * 32, bj = blockIdx.x * 32;  // bi: k, bj: n
  const int r = threadIdx.x >> 3, c4 = (threadIdx.x & 7) * 4;
  float4 f = *(const float4*)&W[(size_t)(bi + r) * DMODEL + bj + c4];
  t[r][c4] = f.x; t[r][c4 + 1] = f.y; t[r][c4 + 2] = f.z; t[r][c4 + 3] = f.w;
  __syncthreads();
  ushort4 u;
  u.x = f2b(t[c4][r]); u.y = f2b(t[c4 + 1][r]);
  u.z = f2b(t[c4 + 2][r]); u.w = f2b(t[c4 + 3][r]);
  *(ushort4*)&WT[(size_t)(bj + r) * DMODEL + bi + c4] = u;
}

// ---------------- Er slice convert: Erb[c][d] = bf16(Er[MAXLEN-S+c][d])
__global__ __launch_bounds__(256) void er_convert(const float* __restrict__ Er,
                                                  unsigned short* __restrict__ Erb) {
  const int i = blockIdx.x * 1024 + threadIdx.x * 4;
  float4 f = *(const float4*)(Er + (size_t)(MAXLEN - S_LEN) * DHEAD + i);
  Erb[i] = f2b(f.x); Erb[i + 1] = f2b(f.y); Erb[i + 2] = f2b(f.z); Erb[i + 3] = f2b(f.w);
}

// ---------------- Projection: Out(bf16) = X(f32)@W + bias, via WT[n][k] bf16.
__global__ __launch_bounds__(256) void proj_mfma(const float* __restrict__ X,
    const unsigned short* __restrict__ WT, const float* __restrict__ bias,
    unsigned short* __restrict__ Out) {
  __shared__ unsigned short As[128 * 64];
  __shared__ unsigned short Bs[128 * 64];
  const int tid = threadIdx.x;
  const int l = tid & 63, wid = tid >> 6;
  const int bm = blockIdx.y * 128, bn = blockIdx.x * 128;
  const int wr = (wid >> 1) * 64, wc = (wid & 1) * 64;
  f32x4 acc[4][4] = {};
  for (int k0 = 0; k0 < DMODEL; k0 += 64) {
    __syncthreads();
#pragma unroll
    for (int r = 0; r < 4; ++r) {  // A: 128x64 f32->bf16
      int s = r * 256 + tid;
      int row = s >> 3, sl = s & 7;
      const float* src = X + (size_t)(bm + row) * DMODEL + k0 + sl * 8;
      float4 f0 = *(const float4*)src;
      float4 f1 = *(const float4*)(src + 4);
      union { unsigned short h[8]; int4 v; } u;
      u.h[0] = f2b(f0.x); u.h[1] = f2b(f0.y); u.h[2] = f2b(f0.z); u.h[3] = f2b(f0.w);
      u.h[4] = f2b(f1.x); u.h[5] = f2b(f1.y); u.h[6] = f2b(f1.z); u.h[7] = f2b(f1.w);
      *(int4*)&As[LDSWZ(row, sl)] = u.v;
    }
#pragma unroll
    for (int r = 0; r < 4; ++r) {  // B: 128x64 bf16 raw
      int s = r * 256 + tid;
      int row = s >> 3, sl = s & 7;
      int4 v = *(const int4*)(WT + (size_t)(bn + row) * DMODEL + k0 + sl * 8);
      *(int4*)&Bs[LDSWZ(row, sl)] = v;
    }
    __syncthreads();
#pragma unroll
    for (int ks = 0; ks < 2; ++ks) {
      bf16x8 a[4], b[4];
#pragma unroll
      for (int f = 0; f < 4; ++f) {
        int row = wr + f * 16 + (l & 15);
        a[f] = *(const bf16x8*)&As[LDSWZ(row, ks * 4 + (l >> 4))];
        int col = wc + f * 16 + (l & 15);
        b[f] = *(const bf16x8*)&Bs[LDSWZ(col, ks * 4 + (l >> 4))];
      }
#pragma unroll
      for (int i = 0; i < 4; ++i)
#pragma unroll
        for (int j = 0; j < 4; ++j)
          acc[i][j] = __builtin_amdgcn_mfma_f32_16x16x32_bf16(a[i], b[j], acc[i][j], 0, 0, 0);
    }
  }
#pragma unroll
  for (int i = 0; i < 4; ++i) {
    int m = bm + wr + i * 16 + ((l >> 4) << 2);
#pragma unroll
    for (int j = 0; j < 4; ++j) {
      int n = bn + wc + j * 16 + (l & 15);
      float bv = bias[n];
#pragma unroll
      for (int e = 0; e < 4; ++e)
        Out[(size_t)(m + e) * DMODEL + n] = f2b(acc[i][j][e] + bv);
    }
  }
}

// ---------------- Fused attention + on-the-fly QEr (G) in LDS.
// Block = (bh, 64 q-rows). Phase A: stage Q rows s0..s0+79. Phase B: G rows s0..s0+64
// (65 x 1024 bf16) via MFMA vs Er col-tiles. Phase C: flash t-loop; rel term read from
// LDS with the flat-skew formula: Srel[s][t] = Gflat[r*1024 + d + 1022 + (d<=0)],
// d = t - s, r = s - s0; 0 at d==1.  (Row r+1's head follows row r's tail contiguously.)
__global__ __launch_bounds__(256) void attn_fused(const unsigned short* __restrict__ qp,
    const unsigned short* __restrict__ kp, const unsigned short* __restrict__ vp,
    const unsigned short* __restrict__ erb, float* __restrict__ out) {
  // XCD-aware remap: keep all 16 s-blocks of one bh on one XCD (L2 reuse of K/V).
  const int o = blockIdx.y * gridDim.x + blockIdx.x;          // 0..1023
  const int lid = (o & 7) * 128 + (o >> 3);                   // bijection
  const int s0 = (lid & 15) * 64;
  const int bh = lid >> 4;
  const int b = bh >> 4, h = bh & 15;

  __shared__ unsigned short lds[66560 + 4096 + 4096 + 4096];  // 157,696 B
  unsigned short* Gs  = lds;                  // 65 x 1024 row-major flat (+ row64 tail)
  unsigned short* KSb = lds + 66560;          // 64x64 swizzled
  unsigned short* VTb = lds + 66560 + 4096;   // 64x64 swizzled
  unsigned short* PSb = lds + 66560 + 8192;   // 4 x (16x64) swizzled

  const int tid = threadIdx.x, ln = tid & 63, w = tid >> 6;
  const int lg = ln >> 4, li = ln & 15;
  const unsigned short* qb = qp + (size_t)b * S_LEN * DMODEL + h * DHEAD;
  const unsigned short* kb = kp + (size_t)b * S_LEN * DMODEL + h * DHEAD;
  const unsigned short* vb = vp + (size_t)b * S_LEN * DMODEL + h * DHEAD;

  // ---- Phase A: stage q rows s0..s0+79 (clamped; rows 64..79 -> VTb)
#pragma unroll
  for (int r = 0; r < 3; ++r) {
    int s = r * 256 + tid;
    if (s < 640) {
      int row = s >> 3, sl = s & 7;
      int srcr = s0 + row; if (srcr > S_LEN - 1) srcr = S_LEN - 1;
      unsigned short* dst = (row < 64) ? &KSb[LDSWZ(row, sl)] : &VTb[LDSWZ(row - 64, sl)];
      *(int4*)dst = *(const int4*)(qb + (size_t)srcr * DMODEL + sl * 8);
    }
  }
  __syncthreads();
  bf16x8 qf[2], qxf[2];
#pragma unroll
  for (int ks = 0; ks < 2; ++ks) {
    qf[ks]  = *(const bf16x8*)&KSb[LDSWZ(w * 16 + li, ks * 4 + lg)];
    qxf[ks] = *(const bf16x8*)&VTb[LDSWZ(li, ks * 4 + lg)];  // rows s0+64..s0+79
  }
  // prologue prefetch of K/V tile 0 (in flight across phase B)
  int4 kpr[2];
#pragma unroll
  for (int r = 0; r < 2; ++r) {
    int s = r * 256 + tid; int row = s >> 3, sl = s & 7;
    kpr[r] = *(const int4*)(kb + (size_t)row * DMODEL + sl * 8);
  }
  const int pr = tid & 31, dh0 = (tid >> 5) * 8;
  int4 vpr0 = *(const int4*)(vb + (size_t)(pr * 2) * DMODEL + dh0);
  int4 vpr1 = *(const int4*)(vb + (size_t)(pr * 2 + 1) * DMODEL + dh0);

  // ---- Phase B: G rows. waves 0..3 cover rows 0..63; wave 0 additionally row 64.
  for (int ct = 0; ct < 16; ++ct) {
    __syncthreads();  // prev iter's VTb frag reads done (ct=0: qxf reads done)
#pragma unroll
    for (int r = 0; r < 2; ++r) {
      int s = r * 256 + tid; int row = s >> 3, sl = s & 7;
      *(int4*)&VTb[LDSWZ(row, sl)] =
          *(const int4*)(erb + (size_t)(ct * 64 + row) * DHEAD + sl * 8);
    }
    __syncthreads();
    f32x4 ga[4] = {}; f32x4 gx[4] = {};
#pragma unroll
    for (int ks = 0; ks < 2; ++ks)
#pragma unroll
      for (int f = 0; f < 4; ++f) {
        bf16x8 erf = *(const bf16x8*)&VTb[LDSWZ(f * 16 + li, ks * 4 + lg)];
        ga[f] = __builtin_amdgcn_mfma_f32_16x16x32_bf16(qf[ks], erf, ga[f], 0, 0, 0);
        if (w == 0)
          gx[f] = __builtin_amdgcn_mfma_f32_16x16x32_bf16(qxf[ks], erf, gx[f], 0, 0, 0);
      }
#pragma unroll
    for (int f = 0; f < 4; ++f)
#pragma unroll
      for (int e = 0; e < 4; ++e)
        Gs[(size_t)(w * 16 + lg * 4 + e) * 1024 + ct * 64 + f * 16 + li] = f2b(ga[f][e]);
    if (w == 0 && lg == 0) {
#pragma unroll
      for (int f = 0; f < 4; ++f)
        Gs[65536 + ct * 64 + f * 16 + li] = f2b(gx[f][0]);  // row s0+64
    }
  }

  // ---- Phase C: flash t-loop
  f32x4 o4[4] = {};
  float m_r[4] = {-1e30f, -1e30f, -1e30f, -1e30f};
  float l_r[4] = {0.f, 0.f, 0.f, 0.f};
  int pre[4];
#pragma unroll
  for (int i = 0; i < 4; ++i) {
    int ri = w * 16 + lg * 4 + i;
    pre[i] = ri * 1023 + 1022 - s0;  // idx = pre + tg + (d<=0)
  }

  for (int ti = 0; ti < 16; ++ti) {
    const int t0 = ti * 64;
    __syncthreads();  // prev tile's KSb/VTb reads done (ti=0: phase-B writes done)
#pragma unroll
    for (int r = 0; r < 2; ++r) {  // commit K tile
      int s = r * 256 + tid; int row = s >> 3, sl = s & 7;
      *(int4*)&KSb[LDSWZ(row, sl)] = kpr[r];
    }
    {  // commit V transposed ([dh][t] pair-packed words)
      union { int4 v; unsigned short hh[8]; } va, vc;
      va.v = vpr0; vc.v = vpr1;
      unsigned int* vtw = (unsigned int*)VTb;
#pragma unroll
      for (int j = 0; j < 8; ++j) {
        int dh = dh0 + j;
        int widx = dh * 32 + (((pr >> 2) ^ (dh & 7)) << 2) + (pr & 3);
        vtw[widx] = (unsigned int)va.hh[j] | ((unsigned int)vc.hh[j] << 16);
      }
    }
    if (ti < 15) {  // prefetch next tile into regs (hidden under this tile's compute)
      const unsigned short* kb2 = kb + (size_t)(t0 + 64) * DMODEL;
#pragma unroll
      for (int r = 0; r < 2; ++r) {
        int s = r * 256 + tid; int row = s >> 3, sl = s & 7;
        kpr[r] = *(const int4*)(kb2 + (size_t)row * DMODEL + sl * 8);
      }
      const unsigned short* vb2 = vb + (size_t)(t0 + 64 + pr * 2) * DMODEL + dh0;
      vpr0 = *(const int4*)vb2;
      vpr1 = *(const int4*)(vb2 + DMODEL);
    }
    __syncthreads();
    // --- QK^T
    f32x4 sa[4] = {};
#pragma unroll
    for (int ks = 0; ks < 2; ++ks)
#pragma unroll
      for (int f = 0; f < 4; ++f) {
        bf16x8 kf = *(const bf16x8*)&KSb[LDSWZ(f * 16 + li, ks * 4 + lg)];
        sa[f] = __builtin_amdgcn_mfma_f32_16x16x32_bf16(qf[ks], kf, sa[f], 0, 0, 0);
      }
    // --- rel from LDS (flat skew) + scale + tile max
    float tmax[4] = {-1e30f, -1e30f, -1e30f, -1e30f};
#pragma unroll
    for (int f = 0; f < 4; ++f) {
#pragma unroll
      for (int i = 0; i < 4; ++i) {
        int tg = t0 + f * 16 + li;
        int d = tg - (s0 + w * 16 + lg * 4 + i);
        int idx = pre[i] + tg + (d <= 0 ? 1 : 0);
        float rel = (d == 1) ? 0.f : b2f(Gs[idx]);
        float sv = (sa[f][i] + rel) * 0.125f;
        sa[f][i] = sv;
        tmax[i] = fmaxf(tmax[i], sv);
      }
    }
#pragma unroll
    for (int off = 8; off >= 1; off >>= 1)
#pragma unroll
      for (int i = 0; i < 4; ++i) tmax[i] = fmaxf(tmax[i], __shfl_xor(tmax[i], off));
    float scale[4];
#pragma unroll
    for (int i = 0; i < 4; ++i) {
      float mn = fmaxf(m_r[i], tmax[i]);
      scale[i] = __expf(m_r[i] - mn);
      m_r[i] = mn;
    }
    // --- P = exp(s-m), bf16 strip per wave, row sums
    float psum[4] = {0.f, 0.f, 0.f, 0.f};
    unsigned short* Pw = PSb + w * 1024;
#pragma unroll
    for (int f = 0; f < 4; ++f) {
#pragma unroll
      for (int i = 0; i < 4; ++i) {
        float p = __expf(sa[f][i] - m_r[i]);
        psum[i] += p;
        int prow = (lg << 2) + i, pcol = f * 16 + li;
        Pw[LDSWZ(prow, pcol >> 3) + (pcol & 7)] = f2b(p);
      }
    }
#pragma unroll
    for (int off = 8; off >= 1; off >>= 1)
#pragma unroll
      for (int i = 0; i < 4; ++i) psum[i] += __shfl_xor(psum[i], off);
#pragma unroll
    for (int i = 0; i < 4; ++i) l_r[i] = l_r[i] * scale[i] + psum[i];
#pragma unroll
    for (int f = 0; f < 4; ++f)
#pragma unroll
      for (int i = 0; i < 4; ++i) o4[f][i] *= scale[i];
    // --- PV
#pragma unroll
    for (int ks = 0; ks < 2; ++ks) {
      bf16x8 pf = *(const bf16x8*)&Pw[LDSWZ(li, ks * 4 + lg)];
#pragma unroll
      for (int f = 0; f < 4; ++f) {
        bf16x8 vf = *(const bf16x8*)&VTb[LDSWZ(f * 16 + li, ks * 4 + lg)];
        o4[f] = __builtin_amdgcn_mfma_f32_16x16x32_bf16(pf, vf, o4[f], 0, 0, 0);
      }
    }
  }
  // ---- epilogue
#pragma unroll
  for (int i = 0; i < 4; ++i) {
    float inv = 1.f / l_r[i];
    int sg = s0 + w * 16 + (lg << 2) + i;
#pragma unroll
    for (int f = 0; f < 4; ++f)
      out[(size_t)(b * S_LEN + sg) * DMODEL + h * DHEAD + f * 16 + li] = o4[f][i] * inv;
  }
}

extern "C" void kernel_launch(void* const* d_in, const int* in_sizes, int n_in,
                              void* d_out, int out_size, void* d_ws, size_t ws_size,
                              hipStream_t stream) {
  (void)in_sizes; (void)n_in; (void)out_size; (void)ws_size;
  const float* q_in = (const float*)d_in[0];
  const float* k_in = (const float*)d_in[1];
  const float* v_in = (const float*)d_in[2];
  const float* Wq   = (const float*)d_in[3];
  const float* bq   = (const float*)d_in[4];
  const float* Wk   = (const float*)d_in[5];
  const float* bk   = (const float*)d_in[6];
  const float* Wv   = (const float*)d_in[7];
  const float* bv   = (const float*)d_in[8];
  const float* Er   = (const float*)d_in[9];
  float* out = (float*)d_out;

  char* ws = (char*)d_ws;
  const size_t MB = (size_t)1 << 20;
  unsigned short* wtq = (unsigned short*)(ws);            // 2 MB
  unsigned short* wtk = (unsigned short*)(ws + 2 * MB);   // 2 MB
  unsigned short* wtv = (unsigned short*)(ws + 4 * MB);   // 2 MB
  unsigned short* erb = (unsigned short*)(ws + 6 * MB);   // 128 KB
  unsigned short* qp  = (unsigned short*)(ws + 8 * MB);   // 8 MB
  unsigned short* kp  = (unsigned short*)(ws + 16 * MB);  // 8 MB
  unsigned short* vp  = (unsigned short*)(ws + 24 * MB);  // 8 MB  (32 MB total)

  dim3 blk(256);
  hipLaunchKernelGGL(wt_convert, dim3(32, 32), blk, 0, stream, Wq, wtq);
  hipLaunchKernelGGL(wt_convert, dim3(32, 32), blk, 0, stream, Wk, wtk);
  hipLaunchKernelGGL(wt_convert, dim3(32, 32), blk, 0, stream, Wv, wtv);
  hipLaunchKernelGGL(er_convert, dim3(64), blk, 0, stream, Er, erb);

  dim3 gproj(DMODEL / 128, (BATCH * S_LEN) / 128);  // (8, 32)
  hipLaunchKernelGGL(proj_mfma, gproj, blk, 0, stream, q_in, wtq, bq, qp);
  hipLaunchKernelGGL(proj_mfma, gproj, blk, 0, stream, k_in, wtk, bk, kp);
  hipLaunchKernelGGL(proj_mfma, gproj, blk, 0, stream, v_in, wtv, bv, vp);

  dim3 gattn(S_LEN / 64, BATCH * NHEADS);  // (16, 64)
  hipLaunchKernelGGL(attn_fused, gattn, blk, 0, stream, qp, kp, vp, erb, out);
}

// Round 6
// 232.458 us; speedup vs baseline: 1.6018x; 1.6018x over previous
//
#include <hip/hip_runtime.h>
#include <hip/hip_bf16.h>
#include <cstdint>

#define S_LEN 1024
#define DMODEL 1024
#define NHEADS 16
#define DHEAD 64
#define MAXLEN 16384
#define BATCH 4

typedef __attribute__((ext_vector_type(8))) short bf16x8;
typedef __attribute__((ext_vector_type(4))) float f32x4;

// RNE f32 -> bf16 bits
__device__ inline unsigned short f2b(float f) {
  unsigned int u = __float_as_uint(f);
  unsigned int r = (u + 0x7FFFu + ((u >> 16) & 1u)) >> 16;
  return (unsigned short)r;
}
__device__ inline float b2f(unsigned short u) {
  return __uint_as_float(((unsigned int)u) << 16);
}

// Swizzled LDS element index for [R][64] bf16 rows (128B): 8 slots of 16B, slot ^= row&7.
#define LDSWZ(row, slot) (((row) << 6) + (((slot) ^ ((row) & 7)) << 3))

// ---------------- W transpose+convert x3: WT[n][k] bf16 = W[k][n] f32
__global__ __launch_bounds__(256) void wt_convert3(
    const float* __restrict__ W0, const float* __restrict__ W1, const float* __restrict__ W2,
    unsigned short* __restrict__ T0, unsigned short* __restrict__ T1, unsigned short* __restrict__ T2) {
  const float* W = (blockIdx.z == 0) ? W0 : (blockIdx.z == 1) ? W1 : W2;
  unsigned short* WT = (blockIdx.z == 0) ? T0 : (blockIdx.z == 1) ? T1 : T2;
  __shared__ float t[32][33];
  const int bi = blockIdx.y * 32, bj = blockIdx.x * 32;  // bi: k, bj: n
  const int r = threadIdx.x >> 3, c4 = (threadIdx.x & 7) * 4;
  float4 f = *(const float4*)&W[(size_t)(bi + r) * DMODEL + bj + c4];
  t[r][c4] = f.x; t[r][c4 + 1] = f.y; t[r][c4 + 2] = f.z; t[r][c4 + 3] = f.w;
  __syncthreads();
  ushort4 u;
  u.x = f2b(t[c4][r]); u.y = f2b(t[c4 + 1][r]);
  u.z = f2b(t[c4 + 2][r]); u.w = f2b(t[c4 + 3][r]);
  *(ushort4*)&WT[(size_t)(bj + r) * DMODEL + bi + c4] = u;
}

// ---------------- Er slice convert: Erb[c][d] = bf16(Er[MAXLEN-S+c][d])
__global__ __launch_bounds__(256) void er_convert(const float* __restrict__ Er,
                                                  unsigned short* __restrict__ Erb) {
  const int i = blockIdx.x * 1024 + threadIdx.x * 4;
  float4 f = *(const float4*)(Er + (size_t)(MAXLEN - S_LEN) * DHEAD + i);
  Erb[i] = f2b(f.x); Erb[i + 1] = f2b(f.y); Erb[i + 2] = f2b(f.z); Erb[i + 3] = f2b(f.w);
}

// ---------------- Projections (all three in one launch, z selects): Out(bf16) = X@W + b
__global__ __launch_bounds__(256) void proj_mfma3(
    const float* __restrict__ X0, const float* __restrict__ X1, const float* __restrict__ X2,
    const unsigned short* __restrict__ T0, const unsigned short* __restrict__ T1,
    const unsigned short* __restrict__ T2,
    const float* __restrict__ b0, const float* __restrict__ b1, const float* __restrict__ b2,
    unsigned short* __restrict__ O0, unsigned short* __restrict__ O1,
    unsigned short* __restrict__ O2) {
  const int z = blockIdx.z;
  const float* X = (z == 0) ? X0 : (z == 1) ? X1 : X2;
  const unsigned short* WT = (z == 0) ? T0 : (z == 1) ? T1 : T2;
  const float* bias = (z == 0) ? b0 : (z == 1) ? b1 : b2;
  unsigned short* Out = (z == 0) ? O0 : (z == 1) ? O1 : O2;
  __shared__ unsigned short As[128 * 64];
  __shared__ unsigned short Bs[128 * 64];
  const int tid = threadIdx.x;
  const int l = tid & 63, wid = tid >> 6;
  const int bm = blockIdx.y * 128, bn = blockIdx.x * 128;
  const int wr = (wid >> 1) * 64, wc = (wid & 1) * 64;
  f32x4 acc[4][4] = {};
  for (int k0 = 0; k0 < DMODEL; k0 += 64) {
    __syncthreads();
#pragma unroll
    for (int r = 0; r < 4; ++r) {  // A: 128x64 f32->bf16
      int s = r * 256 + tid;
      int row = s >> 3, sl = s & 7;
      const float* src = X + (size_t)(bm + row) * DMODEL + k0 + sl * 8;
      float4 f0 = *(const float4*)src;
      float4 f1 = *(const float4*)(src + 4);
      union { unsigned short h[8]; int4 v; } u;
      u.h[0] = f2b(f0.x); u.h[1] = f2b(f0.y); u.h[2] = f2b(f0.z); u.h[3] = f2b(f0.w);
      u.h[4] = f2b(f1.x); u.h[5] = f2b(f1.y); u.h[6] = f2b(f1.z); u.h[7] = f2b(f1.w);
      *(int4*)&As[LDSWZ(row, sl)] = u.v;
    }
#pragma unroll
    for (int r = 0; r < 4; ++r) {  // B: 128x64 bf16 raw
      int s = r * 256 + tid;
      int row = s >> 3, sl = s & 7;
      int4 v = *(const int4*)(WT + (size_t)(bn + row) * DMODEL + k0 + sl * 8);
      *(int4*)&Bs[LDSWZ(row, sl)] = v;
    }
    __syncthreads();
#pragma unroll
    for (int ks = 0; ks < 2; ++ks) {
      bf16x8 a[4], b[4];
#pragma unroll
      for (int f = 0; f < 4; ++f) {
        int row = wr + f * 16 + (l & 15);
        a[f] = *(const bf16x8*)&As[LDSWZ(row, ks * 4 + (l >> 4))];
        int col = wc + f * 16 + (l & 15);
        b[f] = *(const bf16x8*)&Bs[LDSWZ(col, ks * 4 + (l >> 4))];
      }
#pragma unroll
      for (int i = 0; i < 4; ++i)
#pragma unroll
        for (int j = 0; j < 4; ++j)
          acc[i][j] = __builtin_amdgcn_mfma_f32_16x16x32_bf16(a[i], b[j], acc[i][j], 0, 0, 0);
    }
  }
#pragma unroll
  for (int i = 0; i < 4; ++i) {
    int m = bm + wr + i * 16 + ((l >> 4) << 2);
#pragma unroll
    for (int j = 0; j < 4; ++j) {
      int n = bn + wc + j * 16 + (l & 15);
      float bv = bias[n];
#pragma unroll
      for (int e = 0; e < 4; ++e)
        Out[(size_t)(m + e) * DMODEL + n] = f2b(acc[i][j][e] + bv);
    }
  }
}

// ---------------- QEr: G(bf16)[s][c] = q . Er[c], per (b,h). M=N=1024, K=64 single stage.
__global__ __launch_bounds__(256) void qer_mfma(const unsigned short* __restrict__ qp,
    const unsigned short* __restrict__ Erb, unsigned short* __restrict__ G, int bh0) {
  const int bh = bh0 + blockIdx.z;
  const int b = bh >> 4, h = bh & 15;
  __shared__ unsigned short As[128 * 64];
  __shared__ unsigned short Bs[128 * 64];
  const int tid = threadIdx.x, l = tid & 63, wid = tid >> 6;
  const int bm = blockIdx.y * 128, bn = blockIdx.x * 128;
  const int wr = (wid >> 1) * 64, wc = (wid & 1) * 64;
  const unsigned short* qb = qp + (size_t)b * S_LEN * DMODEL + h * DHEAD;
  unsigned short* Gc = G + (size_t)blockIdx.z * S_LEN * S_LEN;
#pragma unroll
  for (int r = 0; r < 4; ++r) {
    int s = r * 256 + tid;
    int row = s >> 3, sl = s & 7;
    *(int4*)&As[LDSWZ(row, sl)] = *(const int4*)(qb + (size_t)(bm + row) * DMODEL + sl * 8);
    *(int4*)&Bs[LDSWZ(row, sl)] = *(const int4*)(Erb + (size_t)(bn + row) * DHEAD + sl * 8);
  }
  __syncthreads();
  f32x4 acc[4][4] = {};
#pragma unroll
  for (int ks = 0; ks < 2; ++ks) {
    bf16x8 a[4], b[4];
#pragma unroll
    for (int f = 0; f < 4; ++f) {
      int row = wr + f * 16 + (l & 15);
      a[f] = *(const bf16x8*)&As[LDSWZ(row, ks * 4 + (l >> 4))];
      int col = wc + f * 16 + (l & 15);
      b[f] = *(const bf16x8*)&Bs[LDSWZ(col, ks * 4 + (l >> 4))];
    }
#pragma unroll
    for (int i = 0; i < 4; ++i)
#pragma unroll
      for (int j = 0; j < 4; ++j)
        acc[i][j] = __builtin_amdgcn_mfma_f32_16x16x32_bf16(a[i], b[j], acc[i][j], 0, 0, 0);
  }
#pragma unroll
  for (int i = 0; i < 4; ++i) {
    int m = bm + wr + i * 16 + ((l >> 4) << 2);
#pragma unroll
    for (int j = 0; j < 4; ++j) {
      int n = bn + wc + j * 16 + (l & 15);
#pragma unroll
      for (int e = 0; e < 4; ++e)
        Gc[(size_t)(m + e) * S_LEN + n] = f2b(acc[i][j][e]);
    }
  }
}

// ---------------- Fused attention, MFMA, with overlapped rel-gather + K/V prefetch.
// rel term via flat-skew: idx = s*1023 + 1022 + tg + (d<=0), d = tg - s; 0 at d==1.
// (G row-major 1024x1024 per chunk slot; max idx = 2^20-1, always in bounds.)
__global__ __launch_bounds__(256) void attn_mfma(const unsigned short* __restrict__ qp,
    const unsigned short* __restrict__ kp, const unsigned short* __restrict__ vp,
    const unsigned short* __restrict__ G, float* __restrict__ out, int bh0) {
  const int bh = bh0 + blockIdx.y;
  const int b = bh >> 4, h = bh & 15;
  const int s0 = blockIdx.x * 64;
  __shared__ unsigned short Qs[64 * 64];
  __shared__ unsigned short Ks[64 * 64];
  __shared__ unsigned short Vt[64 * 64];   // [dh][t], pair-packed + swizzled
  __shared__ unsigned short Ps[4][16 * 64];
  const int tid = threadIdx.x, l = tid & 63, w = tid >> 6;
  const int lg = l >> 4, li = l & 15;
  const unsigned short* qb = qp + (size_t)b * S_LEN * DMODEL + h * DHEAD;
  const unsigned short* kb = kp + (size_t)b * S_LEN * DMODEL + h * DHEAD;
  const unsigned short* vb = vp + (size_t)b * S_LEN * DMODEL + h * DHEAD;
  const unsigned short* Gb = G + (size_t)blockIdx.y * S_LEN * S_LEN;

#pragma unroll
  for (int r = 0; r < 2; ++r) {  // stage Q 64x64
    int s = r * 256 + tid;
    int row = s >> 3, sl = s & 7;
    *(int4*)&Qs[LDSWZ(row, sl)] = *(const int4*)(qb + (size_t)(s0 + row) * DMODEL + sl * 8);
  }
  __syncthreads();
  bf16x8 qf[2];
#pragma unroll
  for (int ks = 0; ks < 2; ++ks)
    qf[ks] = *(const bf16x8*)&Qs[LDSWZ(w * 16 + li, ks * 4 + lg)];

  // prologue prefetch of K/V tile 0 into registers
  int4 kpr[2];
#pragma unroll
  for (int r = 0; r < 2; ++r) {
    int s = r * 256 + tid; int row = s >> 3, sl = s & 7;
    kpr[r] = *(const int4*)(kb + (size_t)row * DMODEL + sl * 8);
  }
  const int pr = tid & 31, dh0 = (tid >> 5) * 8;
  int4 vpr0 = *(const int4*)(vb + (size_t)(pr * 2) * DMODEL + dh0);
  int4 vpr1 = *(const int4*)(vb + (size_t)(pr * 2 + 1) * DMODEL + dh0);

  f32x4 o4[4] = {};
  float m_r[4] = {-1e30f, -1e30f, -1e30f, -1e30f};
  float l_r[4] = {0.f, 0.f, 0.f, 0.f};
  int sg[4], pre[4];
#pragma unroll
  for (int i = 0; i < 4; ++i) {
    sg[i] = s0 + w * 16 + (lg << 2) + i;
    pre[i] = sg[i] * 1023 + 1022;
  }

  for (int ti = 0; ti < 16; ++ti) {
    const int t0 = ti * 64;
    __syncthreads();  // prev tile's Ks/Vt/Ps readers done; drains reg prefetches
#pragma unroll
    for (int r = 0; r < 2; ++r) {  // commit K tile
      int s = r * 256 + tid; int row = s >> 3, sl = s & 7;
      *(int4*)&Ks[LDSWZ(row, sl)] = kpr[r];
    }
    {  // commit V transposed ([dh][t] pair-packed words)
      union { int4 v; unsigned short hh[8]; } va, vc;
      va.v = vpr0; vc.v = vpr1;
      unsigned int* vtw = (unsigned int*)Vt;
#pragma unroll
      for (int j = 0; j < 8; ++j) {
        int dh = dh0 + j;
        int widx = dh * 32 + (((pr >> 2) ^ (dh & 7)) << 2) + (pr & 3);
        vtw[widx] = (unsigned int)va.hh[j] | ((unsigned int)vc.hh[j] << 16);
      }
    }
    __syncthreads();  // K/V visible
    // --- overlapped issues: rel gather for THIS tile + K/V prefetch for NEXT tile.
    unsigned int rv[4][4];
#pragma unroll
    for (int f = 0; f < 4; ++f)
#pragma unroll
      for (int i = 0; i < 4; ++i) {
        int tg = t0 + f * 16 + li;
        int dd = tg - sg[i];
        rv[f][i] = Gb[pre[i] + tg + (dd <= 0 ? 1 : 0)];
      }
    if (ti < 15) {
      const unsigned short* kb2 = kb + (size_t)(t0 + 64) * DMODEL;
#pragma unroll
      for (int r = 0; r < 2; ++r) {
        int s = r * 256 + tid; int row = s >> 3, sl = s & 7;
        kpr[r] = *(const int4*)(kb2 + (size_t)row * DMODEL + sl * 8);
      }
      const unsigned short* vb2 = vb + (size_t)(t0 + 64 + pr * 2) * DMODEL + dh0;
      vpr0 = *(const int4*)vb2;
      vpr1 = *(const int4*)(vb2 + DMODEL);
    }
    // --- QK^T (covers the in-flight loads above)
    f32x4 sa[4] = {};
#pragma unroll
    for (int ks = 0; ks < 2; ++ks)
#pragma unroll
      for (int f = 0; f < 4; ++f) {
        bf16x8 kf = *(const bf16x8*)&Ks[LDSWZ(f * 16 + li, ks * 4 + lg)];
        sa[f] = __builtin_amdgcn_mfma_f32_16x16x32_bf16(qf[ks], kf, sa[f], 0, 0, 0);
      }
    // --- apply rel + scale + tile max
    float tmax[4] = {-1e30f, -1e30f, -1e30f, -1e30f};
#pragma unroll
    for (int f = 0; f < 4; ++f) {
#pragma unroll
      for (int i = 0; i < 4; ++i) {
        int tg = t0 + f * 16 + li;
        int dd = tg - sg[i];
        float rel = (dd == 1) ? 0.f : b2f((unsigned short)rv[f][i]);
        float sv = (sa[f][i] + rel) * 0.125f;
        sa[f][i] = sv;
        tmax[i] = fmaxf(tmax[i], sv);
      }
    }
#pragma unroll
    for (int off = 8; off >= 1; off >>= 1)
#pragma unroll
      for (int i = 0; i < 4; ++i) tmax[i] = fmaxf(tmax[i], __shfl_xor(tmax[i], off));
    float scale[4];
#pragma unroll
    for (int i = 0; i < 4; ++i) {
      float mn = fmaxf(m_r[i], tmax[i]);
      scale[i] = __expf(m_r[i] - mn);
      m_r[i] = mn;
    }
    // --- P = exp(s-m), bf16 strip per wave, row sums
    float psum[4] = {0.f, 0.f, 0.f, 0.f};
    unsigned short* Pw = &Ps[w][0];
#pragma unroll
    for (int f = 0; f < 4; ++f) {
#pragma unroll
      for (int i = 0; i < 4; ++i) {
        float p = __expf(sa[f][i] - m_r[i]);
        psum[i] += p;
        int prow = (lg << 2) + i, pcol = f * 16 + li;
        Pw[LDSWZ(prow, pcol >> 3) + (pcol & 7)] = f2b(p);
      }
    }
#pragma unroll
    for (int off = 8; off >= 1; off >>= 1)
#pragma unroll
      for (int i = 0; i < 4; ++i) psum[i] += __shfl_xor(psum[i], off);
#pragma unroll
    for (int i = 0; i < 4; ++i) l_r[i] = l_r[i] * scale[i] + psum[i];
#pragma unroll
    for (int f = 0; f < 4; ++f)
#pragma unroll
      for (int i = 0; i < 4; ++i) o4[f][i] *= scale[i];
    // --- PV
#pragma unroll
    for (int ks = 0; ks < 2; ++ks) {
      bf16x8 pf = *(const bf16x8*)&Pw[LDSWZ(li, ks * 4 + lg)];
#pragma unroll
      for (int f = 0; f < 4; ++f) {
        bf16x8 vf = *(const bf16x8*)&Vt[LDSWZ(f * 16 + li, ks * 4 + lg)];
        o4[f] = __builtin_amdgcn_mfma_f32_16x16x32_bf16(pf, vf, o4[f], 0, 0, 0);
      }
    }
  }
  // ---- epilogue
#pragma unroll
  for (int i = 0; i < 4; ++i) {
    float inv = 1.f / l_r[i];
#pragma unroll
    for (int f = 0; f < 4; ++f)
      out[(size_t)(b * S_LEN + sg[i]) * DMODEL + h * DHEAD + f * 16 + li] = o4[f][i] * inv;
  }
}

extern "C" void kernel_launch(void* const* d_in, const int* in_sizes, int n_in,
                              void* d_out, int out_size, void* d_ws, size_t ws_size,
                              hipStream_t stream) {
  (void)in_sizes; (void)n_in; (void)out_size;
  const float* q_in = (const float*)d_in[0];
  const float* k_in = (const float*)d_in[1];
  const float* v_in = (const float*)d_in[2];
  const float* Wq   = (const float*)d_in[3];
  const float* bq   = (const float*)d_in[4];
  const float* Wk   = (const float*)d_in[5];
  const float* bk   = (const float*)d_in[6];
  const float* Wv   = (const float*)d_in[7];
  const float* bv   = (const float*)d_in[8];
  const float* Er   = (const float*)d_in[9];
  float* out = (float*)d_out;

  char* ws = (char*)d_ws;
  const size_t MB = (size_t)1 << 20;
  unsigned short* wtq = (unsigned short*)(ws);            // 2 MB
  unsigned short* wtk = (unsigned short*)(ws + 2 * MB);   // 2 MB
  unsigned short* wtv = (unsigned short*)(ws + 4 * MB);   // 2 MB
  unsigned short* erb = (unsigned short*)(ws + 6 * MB);   // 128 KB
  unsigned short* qp  = (unsigned short*)(ws + 8 * MB);   // 8 MB
  unsigned short* kp  = (unsigned short*)(ws + 16 * MB);  // 8 MB
  unsigned short* vp  = (unsigned short*)(ws + 24 * MB);  // 8 MB
  unsigned short* G   = (unsigned short*)(ws + 32 * MB);  // nb * 2 MB

  const size_t gavail = (ws_size > 32 * MB) ? (ws_size - 32 * MB) : 0;
  int chunk = (int)(gavail / (2 * MB));
  if (chunk < 1) chunk = 1;
  if (chunk > 64) chunk = 64;

  dim3 blk(256);
  hipLaunchKernelGGL(wt_convert3, dim3(32, 32, 3), blk, 0, stream,
                     Wq, Wk, Wv, wtq, wtk, wtv);
  hipLaunchKernelGGL(er_convert, dim3(64), blk, 0, stream, Er, erb);

  dim3 gproj(DMODEL / 128, (BATCH * S_LEN) / 128, 3);  // (8, 32, 3)
  hipLaunchKernelGGL(proj_mfma3, gproj, blk, 0, stream,
                     q_in, k_in, v_in, wtq, wtk, wtv, bq, bk, bv, qp, kp, vp);

  for (int bh0 = 0; bh0 < BATCH * NHEADS; bh0 += chunk) {
    int nb = BATCH * NHEADS - bh0;
    if (nb > chunk) nb = chunk;
    dim3 gqer(S_LEN / 128, S_LEN / 128, nb);  // (8, 8, nb)
    hipLaunchKernelGGL(qer_mfma, gqer, blk, 0, stream, qp, erb, G, bh0);
    dim3 gattn(S_LEN / 64, nb);               // (16, nb)
    hipLaunchKernelGGL(attn_mfma, gattn, blk, 0, stream, qp, kp, vp, G, out, bh0);
  }
}

// Round 8
// 215.367 us; speedup vs baseline: 1.7289x; 1.0794x over previous
//
#include <hip/hip_runtime.h>
#include <hip/hip_bf16.h>
#include <cstdint>

#define S_LEN 1024
#define DMODEL 1024
#define NHEADS 16
#define DHEAD 64
#define MAXLEN 16384
#define BATCH 4

typedef __attribute__((ext_vector_type(8))) short bf16x8;
typedef __attribute__((ext_vector_type(4))) float f32x4;

// RNE f32 -> bf16 bits
__device__ inline unsigned short f2b(float f) {
  unsigned int u = __float_as_uint(f);
  unsigned int r = (u + 0x7FFFu + ((u >> 16) & 1u)) >> 16;
  return (unsigned short)r;
}
__device__ inline float b2f(unsigned short u) {
  return __uint_as_float(((unsigned int)u) << 16);
}

// Swizzled LDS element index for [R][64] bf16 rows (128B): 8 slots of 16B, slot ^= row&7.
#define LDSWZ(row, slot) (((row) << 6) + (((slot) ^ ((row) & 7)) << 3))

// ---------------- W transpose+convert x3: WT[n][k] bf16 = W[k][n] f32
__global__ __launch_bounds__(256) void wt_convert3(
    const float* __restrict__ W0, const float* __restrict__ W1, const float* __restrict__ W2,
    unsigned short* __restrict__ T0, unsigned short* __restrict__ T1, unsigned short* __restrict__ T2) {
  const float* W = (blockIdx.z == 0) ? W0 : (blockIdx.z == 1) ? W1 : W2;
  unsigned short* WT = (blockIdx.z == 0) ? T0 : (blockIdx.z == 1) ? T1 : T2;
  __shared__ float t[32][33];
  const int bi = blockIdx.y * 32, bj = blockIdx.x * 32;  // bi: k, bj: n
  const int r = threadIdx.x >> 3, c4 = (threadIdx.x & 7) * 4;
  float4 f = *(const float4*)&W[(size_t)(bi + r) * DMODEL + bj + c4];
  t[r][c4] = f.x; t[r][c4 + 1] = f.y; t[r][c4 + 2] = f.z; t[r][c4 + 3] = f.w;
  __syncthreads();
  ushort4 u;
  u.x = f2b(t[c4][r]); u.y = f2b(t[c4 + 1][r]);
  u.z = f2b(t[c4 + 2][r]); u.w = f2b(t[c4 + 3][r]);
  *(ushort4*)&WT[(size_t)(bj + r) * DMODEL + bi + c4] = u;
}

// ---------------- Er slice convert: Erb[c][d] = bf16(Er[MAXLEN-S+c][d])
__global__ __launch_bounds__(256) void er_convert(const float* __restrict__ Er,
                                                  unsigned short* __restrict__ Erb) {
  const int i = blockIdx.x * 1024 + threadIdx.x * 4;
  float4 f = *(const float4*)(Er + (size_t)(MAXLEN - S_LEN) * DHEAD + i);
  Erb[i] = f2b(f.x); Erb[i + 1] = f2b(f.y); Erb[i + 2] = f2b(f.z); Erb[i + 3] = f2b(f.w);
}

// ---------------- Projections (all three in one launch, z selects): Out(bf16) = X@W + b
__global__ __launch_bounds__(256) void proj_mfma3(
    const float* __restrict__ X0, const float* __restrict__ X1, const float* __restrict__ X2,
    const unsigned short* __restrict__ T0, const unsigned short* __restrict__ T1,
    const unsigned short* __restrict__ T2,
    const float* __restrict__ b0, const float* __restrict__ b1, const float* __restrict__ b2,
    unsigned short* __restrict__ O0, unsigned short* __restrict__ O1,
    unsigned short* __restrict__ O2) {
  const int z = blockIdx.z;
  const float* X = (z == 0) ? X0 : (z == 1) ? X1 : X2;
  const unsigned short* WT = (z == 0) ? T0 : (z == 1) ? T1 : T2;
  const float* bias = (z == 0) ? b0 : (z == 1) ? b1 : b2;
  unsigned short* Out = (z == 0) ? O0 : (z == 1) ? O1 : O2;
  __shared__ unsigned short As[128 * 64];
  __shared__ unsigned short Bs[128 * 64];
  const int tid = threadIdx.x;
  const int l = tid & 63, wid = tid >> 6;
  const int bm = blockIdx.y * 128, bn = blockIdx.x * 128;
  const int wr = (wid >> 1) * 64, wc = (wid & 1) * 64;
  f32x4 acc[4][4] = {};
  for (int k0 = 0; k0 < DMODEL; k0 += 64) {
    __syncthreads();
#pragma unroll
    for (int r = 0; r < 4; ++r) {  // A: 128x64 f32->bf16
      int s = r * 256 + tid;
      int row = s >> 3, sl = s & 7;
      const float* src = X + (size_t)(bm + row) * DMODEL + k0 + sl * 8;
      float4 f0 = *(const float4*)src;
      float4 f1 = *(const float4*)(src + 4);
      union { unsigned short h[8]; int4 v; } u;
      u.h[0] = f2b(f0.x); u.h[1] = f2b(f0.y); u.h[2] = f2b(f0.z); u.h[3] = f2b(f0.w);
      u.h[4] = f2b(f1.x); u.h[5] = f2b(f1.y); u.h[6] = f2b(f1.z); u.h[7] = f2b(f1.w);
      *(int4*)&As[LDSWZ(row, sl)] = u.v;
    }
#pragma unroll
    for (int r = 0; r < 4; ++r) {  // B: 128x64 bf16 raw
      int s = r * 256 + tid;
      int row = s >> 3, sl = s & 7;
      int4 v = *(const int4*)(WT + (size_t)(bn + row) * DMODEL + k0 + sl * 8);
      *(int4*)&Bs[LDSWZ(row, sl)] = v;
    }
    __syncthreads();
#pragma unroll
    for (int ks = 0; ks < 2; ++ks) {
      bf16x8 a[4], b[4];
#pragma unroll
      for (int f = 0; f < 4; ++f) {
        int row = wr + f * 16 + (l & 15);
        a[f] = *(const bf16x8*)&As[LDSWZ(row, ks * 4 + (l >> 4))];
        int col = wc + f * 16 + (l & 15);
        b[f] = *(const bf16x8*)&Bs[LDSWZ(col, ks * 4 + (l >> 4))];
      }
#pragma unroll
      for (int i = 0; i < 4; ++i)
#pragma unroll
        for (int j = 0; j < 4; ++j)
          acc[i][j] = __builtin_amdgcn_mfma_f32_16x16x32_bf16(a[i], b[j], acc[i][j], 0, 0, 0);
    }
  }
#pragma unroll
  for (int i = 0; i < 4; ++i) {
    int m = bm + wr + i * 16 + ((l >> 4) << 2);
#pragma unroll
    for (int j = 0; j < 4; ++j) {
      int n = bn + wc + j * 16 + (l & 15);
      float bv = bias[n];
#pragma unroll
      for (int e = 0; e < 4; ++e)
        Out[(size_t)(m + e) * DMODEL + n] = f2b(acc[i][j][e] + bv);
    }
  }
}

// ---------------- QEr: G(bf16)[s][c] = q . Er[c], per (b,h). M=N=1024, K=64 single stage.
__global__ __launch_bounds__(256) void qer_mfma(const unsigned short* __restrict__ qp,
    const unsigned short* __restrict__ Erb, unsigned short* __restrict__ G, int bh0) {
  const int bh = bh0 + blockIdx.z;
  const int b = bh >> 4, h = bh & 15;
  __shared__ unsigned short As[128 * 64];
  __shared__ unsigned short Bs[128 * 64];
  const int tid = threadIdx.x, l = tid & 63, wid = tid >> 6;
  const int bm = blockIdx.y * 128, bn = blockIdx.x * 128;
  const int wr = (wid >> 1) * 64, wc = (wid & 1) * 64;
  const unsigned short* qb = qp + (size_t)b * S_LEN * DMODEL + h * DHEAD;
  unsigned short* Gc = G + (size_t)blockIdx.z * S_LEN * S_LEN;
#pragma unroll
  for (int r = 0; r < 4; ++r) {
    int s = r * 256 + tid;
    int row = s >> 3, sl = s & 7;
    *(int4*)&As[LDSWZ(row, sl)] = *(const int4*)(qb + (size_t)(bm + row) * DMODEL + sl * 8);
    *(int4*)&Bs[LDSWZ(row, sl)] = *(const int4*)(Erb + (size_t)(bn + row) * DHEAD + sl * 8);
  }
  __syncthreads();
  f32x4 acc[4][4] = {};
#pragma unroll
  for (int ks = 0; ks < 2; ++ks) {
    bf16x8 a[4], b[4];
#pragma unroll
    for (int f = 0; f < 4; ++f) {
      int row = wr + f * 16 + (l & 15);
      a[f] = *(const bf16x8*)&As[LDSWZ(row, ks * 4 + (l >> 4))];
      int col = wc + f * 16 + (l & 15);
      b[f] = *(const bf16x8*)&Bs[LDSWZ(col, ks * 4 + (l >> 4))];
    }
#pragma unroll
    for (int i = 0; i < 4; ++i)
#pragma unroll
      for (int j = 0; j < 4; ++j)
        acc[i][j] = __builtin_amdgcn_mfma_f32_16x16x32_bf16(a[i], b[j], acc[i][j], 0, 0, 0);
  }
#pragma unroll
  for (int i = 0; i < 4; ++i) {
    int m = bm + wr + i * 16 + ((l >> 4) << 2);
#pragma unroll
    for (int j = 0; j < 4; ++j) {
      int n = bn + wc + j * 16 + (l & 15);
#pragma unroll
      for (int e = 0; e < 4; ++e)
        Gc[(size_t)(m + e) * S_LEN + n] = f2b(acc[i][j][e]);
    }
  }
}

// ---------------- Fused attention, MFMA. Double-buffered K/V (one barrier per tile),
// rel gather prefetched one full tile ahead, K/V global loads two tiles ahead.
// rel flat-skew: idx = s*1023 + 1022 + tg + (d<=0), d = tg - s; 0 at d==1.
__global__ __launch_bounds__(256) void attn_mfma(const unsigned short* __restrict__ qp,
    const unsigned short* __restrict__ kp, const unsigned short* __restrict__ vp,
    const unsigned short* __restrict__ G, float* __restrict__ out, int bh0, int nb) {
  // XCD-aware bijection: nwg = 16*nb (always %8==0). XCD x gets a contiguous lid chunk
  // -> all 16 s-blocks of a bh share one XCD's L2 for K/V.
  const int o = blockIdx.y * 16 + blockIdx.x;
  const int q8 = nb * 2;                       // nwg / 8
  const int lid = (o & 7) * q8 + (o >> 3);
  const int s0 = (lid & 15) * 64;
  const int bhl = lid >> 4;
  const int bh = bh0 + bhl;
  const int b = bh >> 4, h = bh & 15;

  __shared__ unsigned short lds[5 * 4096];     // 40 KB -> 4 blocks/CU
  // layout: [0,4096) K buf0 | [4096,8192) K buf1 | [8192,12288) V buf0
  //         [12288,16384) V buf1 | [16384,20480) Q staging then P strips

  const int tid = threadIdx.x, l = tid & 63, w = tid >> 6;
  const int lg = l >> 4, li = l & 15;
  const unsigned short* qb = qp + (size_t)b * S_LEN * DMODEL + h * DHEAD;
  const unsigned short* kb = kp + (size_t)b * S_LEN * DMODEL + h * DHEAD;
  const unsigned short* vb = vp + (size_t)b * S_LEN * DMODEL + h * DHEAD;
  const unsigned short* Gb = G + (size_t)bhl * S_LEN * S_LEN;

  const int pr = tid & 31, dh0 = (tid >> 5) * 8;

  // ---- prologue: stage Q; load K/V tile 0
  {
    unsigned short* PQ = lds + 16384;
#pragma unroll
    for (int r = 0; r < 2; ++r) {
      int s = r * 256 + tid;
      int row = s >> 3, sl = s & 7;
      *(int4*)&PQ[LDSWZ(row, sl)] = *(const int4*)(qb + (size_t)(s0 + row) * DMODEL + sl * 8);
    }
  }
  int4 kpr[2]; int4 vpr0, vpr1;
#pragma unroll
  for (int r = 0; r < 2; ++r) {
    int s = r * 256 + tid; int row = s >> 3, sl = s & 7;
    kpr[r] = *(const int4*)(kb + (size_t)row * DMODEL + sl * 8);
  }
  vpr0 = *(const int4*)(vb + (size_t)(pr * 2) * DMODEL + dh0);
  vpr1 = *(const int4*)(vb + (size_t)(pr * 2 + 1) * DMODEL + dh0);
  __syncthreads();                             // Q visible; K/V tile-0 regs drained
  bf16x8 qf[2];
#pragma unroll
  for (int ks = 0; ks < 2; ++ks)
    qf[ks] = *(const bf16x8*)&lds[16384 + LDSWZ(w * 16 + li, ks * 4 + lg)];

  // commit tile 0 into buf 0
#pragma unroll
  for (int r = 0; r < 2; ++r) {
    int s = r * 256 + tid; int row = s >> 3, sl = s & 7;
    *(int4*)&lds[LDSWZ(row, sl)] = kpr[r];
  }
  {
    union { int4 v; unsigned short hh[8]; } va, vc;
    va.v = vpr0; vc.v = vpr1;
    unsigned int* vtw = (unsigned int*)(lds + 8192);
#pragma unroll
    for (int j = 0; j < 8; ++j) {
      int dh = dh0 + j;
      int widx = dh * 32 + (((pr >> 2) ^ (dh & 7)) << 2) + (pr & 3);
      vtw[widx] = (unsigned int)va.hh[j] | ((unsigned int)vc.hh[j] << 16);
    }
  }
  // prefetch K/V tile 1 regs + rel values tile 0
  int sg[4], pre[4];
#pragma unroll
  for (int i = 0; i < 4; ++i) {
    sg[i] = s0 + w * 16 + (lg << 2) + i;
    pre[i] = sg[i] * 1023 + 1022;
  }
#pragma unroll
  for (int r = 0; r < 2; ++r) {
    int s = r * 256 + tid; int row = s >> 3, sl = s & 7;
    kpr[r] = *(const int4*)(kb + (size_t)(64 + row) * DMODEL + sl * 8);
  }
  vpr0 = *(const int4*)(vb + (size_t)(64 + pr * 2) * DMODEL + dh0);
  vpr1 = *(const int4*)(vb + (size_t)(64 + pr * 2 + 1) * DMODEL + dh0);
  unsigned int rv[4][4];
#pragma unroll
  for (int f = 0; f < 4; ++f)
#pragma unroll
    for (int i = 0; i < 4; ++i) {
      int tg = f * 16 + li;
      rv[f][i] = Gb[pre[i] + tg + ((tg - sg[i]) <= 0 ? 1 : 0)];
    }

  f32x4 o4[4] = {};
  float m_r[4] = {-1e30f, -1e30f, -1e30f, -1e30f};
  float l_r[4] = {0.f, 0.f, 0.f, 0.f};

  for (int ti = 0; ti < 16; ++ti) {
    const int t0 = ti * 64;
    const int p = ti & 1;
    unsigned short* Ksp = lds + p * 4096;
    unsigned short* Vtp = lds + 8192 + p * 4096;
    __syncthreads();  // prev readers of buf 1-p done; all prefetch loads drained
    if (ti < 15) {    // commit tile ti+1 (regs loaded last iteration) into buf 1-p
      unsigned short* Ksn = lds + (1 - p) * 4096;
      unsigned short* Vtn = lds + 8192 + (1 - p) * 4096;
#pragma unroll
      for (int r = 0; r < 2; ++r) {
        int s = r * 256 + tid; int row = s >> 3, sl = s & 7;
        *(int4*)&Ksn[LDSWZ(row, sl)] = kpr[r];
      }
      union { int4 v; unsigned short hh[8]; } va, vc;
      va.v = vpr0; vc.v = vpr1;
      unsigned int* vtw = (unsigned int*)Vtn;
#pragma unroll
      for (int j = 0; j < 8; ++j) {
        int dh = dh0 + j;
        int widx = dh * 32 + (((pr >> 2) ^ (dh & 7)) << 2) + (pr & 3);
        vtw[widx] = (unsigned int)va.hh[j] | ((unsigned int)vc.hh[j] << 16);
      }
    }
    // --- QK^T from buf p (committed last iteration; visible via top barrier)
    f32x4 sa[4] = {};
#pragma unroll
    for (int ks = 0; ks < 2; ++ks)
#pragma unroll
      for (int f = 0; f < 4; ++f) {
        bf16x8 kf = *(const bf16x8*)&Ksp[LDSWZ(f * 16 + li, ks * 4 + lg)];
        sa[f] = __builtin_amdgcn_mfma_f32_16x16x32_bf16(qf[ks], kf, sa[f], 0, 0, 0);
      }
    // --- apply rel (rv loaded a full tile ago) + scale + tile max
    float tmax[4] = {-1e30f, -1e30f, -1e30f, -1e30f};
#pragma unroll
    for (int f = 0; f < 4; ++f) {
#pragma unroll
      for (int i = 0; i < 4; ++i) {
        int tg = t0 + f * 16 + li;
        int dd = tg - sg[i];
        float rel = (dd == 1) ? 0.f : b2f((unsigned short)rv[f][i]);
        float sv = (sa[f][i] + rel) * 0.125f;
        sa[f][i] = sv;
        tmax[i] = fmaxf(tmax[i], sv);
      }
    }
    // --- issue next-tile prefetches (covered by softmax + PV + next barrier + QK)
    if (ti < 14) {
      const unsigned short* kb2 = kb + (size_t)(t0 + 128) * DMODEL;
#pragma unroll
      for (int r = 0; r < 2; ++r) {
        int s = r * 256 + tid; int row = s >> 3, sl = s & 7;
        kpr[r] = *(const int4*)(kb2 + (size_t)row * DMODEL + sl * 8);
      }
      const unsigned short* vb2 = vb + (size_t)(t0 + 128 + pr * 2) * DMODEL + dh0;
      vpr0 = *(const int4*)vb2;
      vpr1 = *(const int4*)(vb2 + DMODEL);
    }
    if (ti < 15) {
      const int t0n = t0 + 64;
#pragma unroll
      for (int f = 0; f < 4; ++f)
#pragma unroll
        for (int i = 0; i < 4; ++i) {
          int tg = t0n + f * 16 + li;
          rv[f][i] = Gb[pre[i] + tg + ((tg - sg[i]) <= 0 ? 1 : 0)];
        }
    }
    // --- online softmax
#pragma unroll
    for (int off = 8; off >= 1; off >>= 1)
#pragma unroll
      for (int i = 0; i < 4; ++i) tmax[i] = fmaxf(tmax[i], __shfl_xor(tmax[i], off));
    float scale[4];
#pragma unroll
    for (int i = 0; i < 4; ++i) {
      float mn = fmaxf(m_r[i], tmax[i]);
      scale[i] = __expf(m_r[i] - mn);
      m_r[i] = mn;
    }
    float psum[4] = {0.f, 0.f, 0.f, 0.f};
    unsigned short* Pw = lds + 16384 + w * 1024;
#pragma unroll
    for (int f = 0; f < 4; ++f) {
#pragma unroll
      for (int i = 0; i < 4; ++i) {
        float pv = __expf(sa[f][i] - m_r[i]);
        psum[i] += pv;
        int prow = (lg << 2) + i, pcol = f * 16 + li;
        Pw[LDSWZ(prow, pcol >> 3) + (pcol & 7)] = f2b(pv);
      }
    }
#pragma unroll
    for (int off = 8; off >= 1; off >>= 1)
#pragma unroll
      for (int i = 0; i < 4; ++i) psum[i] += __shfl_xor(psum[i], off);
#pragma unroll
    for (int i = 0; i < 4; ++i) l_r[i] = l_r[i] * scale[i] + psum[i];
#pragma unroll
    for (int f = 0; f < 4; ++f)
#pragma unroll
      for (int i = 0; i < 4; ++i) o4[f][i] *= scale[i];
    // --- PV from buf p (Pw writes are wave-local; wave sees own writes in order)
#pragma unroll
    for (int ks = 0; ks < 2; ++ks) {
      bf16x8 pf = *(const bf16x8*)&Pw[LDSWZ(li, ks * 4 + lg)];
#pragma unroll
      for (int f = 0; f < 4; ++f) {
        bf16x8 vf = *(const bf16x8*)&Vtp[LDSWZ(f * 16 + li, ks * 4 + lg)];
        o4[f] = __builtin_amdgcn_mfma_f32_16x16x32_bf16(pf, vf, o4[f], 0, 0, 0);
      }
    }
  }
  // ---- epilogue
#pragma unroll
  for (int i = 0; i < 4; ++i) {
    float inv = 1.f / l_r[i];
#pragma unroll
    for (int f = 0; f < 4; ++f)
      out[(size_t)(b * S_LEN + sg[i]) * DMODEL + h * DHEAD + f * 16 + li] = o4[f][i] * inv;
  }
}

extern "C" void kernel_launch(void* const* d_in, const int* in_sizes, int n_in,
                              void* d_out, int out_size, void* d_ws, size_t ws_size,
                              hipStream_t stream) {
  (void)in_sizes; (void)n_in; (void)out_size;
  const float* q_in = (const float*)d_in[0];
  const float* k_in = (const float*)d_in[1];
  const float* v_in = (const float*)d_in[2];
  const float* Wq   = (const float*)d_in[3];
  const float* bq   = (const float*)d_in[4];
  const float* Wk   = (const float*)d_in[5];
  const float* bk   = (const float*)d_in[6];
  const float* Wv   = (const float*)d_in[7];
  const float* bv   = (const float*)d_in[8];
  const float* Er   = (const float*)d_in[9];
  float* out = (float*)d_out;

  char* ws = (char*)d_ws;
  const size_t MB = (size_t)1 << 20;
  unsigned short* wtq = (unsigned short*)(ws);            // 2 MB
  unsigned short* wtk = (unsigned short*)(ws + 2 * MB);   // 2 MB
  unsigned short* wtv = (unsigned short*)(ws + 4 * MB);   // 2 MB
  unsigned short* erb = (unsigned short*)(ws + 6 * MB);   // 128 KB
  unsigned short* qp  = (unsigned short*)(ws + 8 * MB);   // 8 MB
  unsigned short* kp  = (unsigned short*)(ws + 16 * MB);  // 8 MB
  unsigned short* vp  = (unsigned short*)(ws + 24 * MB);  // 8 MB
  unsigned short* G   = (unsigned short*)(ws + 32 * MB);  // nb * 2 MB

  const size_t gavail = (ws_size > 32 * MB) ? (ws_size - 32 * MB) : 0;
  int chunk = (int)(gavail / (2 * MB));
  if (chunk < 1) chunk = 1;
  if (chunk > 64) chunk = 64;

  dim3 blk(256);
  hipLaunchKernelGGL(wt_convert3, dim3(32, 32, 3), blk, 0, stream,
                     Wq, Wk, Wv, wtq, wtk, wtv);
  hipLaunchKernelGGL(er_convert, dim3(64), blk, 0, stream, Er, erb);

  dim3 gproj(DMODEL / 128, (BATCH * S_LEN) / 128, 3);  // (8, 32, 3)
  hipLaunchKernelGGL(proj_mfma3, gproj, blk, 0, stream,
                     q_in, k_in, v_in, wtq, wtk, wtv, bq, bk, bv, qp, kp, vp);

  for (int bh0 = 0; bh0 < BATCH * NHEADS; bh0 += chunk) {
    int nb = BATCH * NHEADS - bh0;
    if (nb > chunk) nb = chunk;
    dim3 gqer(S_LEN / 128, S_LEN / 128, nb);  // (8, 8, nb)
    hipLaunchKernelGGL(qer_mfma, gqer, blk, 0, stream, qp, erb, G, bh0);
    dim3 gattn(S_LEN / 64, nb);               // (16, nb)
    hipLaunchKernelGGL(attn_mfma, gattn, blk, 0, stream, qp, kp, vp, G, out, bh0, nb);
  }
}